// Round 1
// baseline (1243.427 us; speedup 1.0000x reference)
//
#include <hip/hip_runtime.h>

// Problem constants (fixed by the reference's setup_inputs)
#define QS_ 512
#define B_  8
#define C_  1024
#define H_  16
#define HC_ 64
#define M_  1536
#define KS_ 512

// ---------------------------------------------------------------------------
// f32 NT GEMM: out[n][j] = sum_k A[n][k] * W[j][k] + bias[j]
// A: 4096x1024 row-major, W: 1024x1024 row-major.
// Grid (64, 16), block 256. 64x64 tile, 4x4 per thread, K-chunk 64.
// LDS pad 65: frag reads are <=2-way bank aliased (free on CDNA4).
// ---------------------------------------------------------------------------
__global__ __launch_bounds__(256) void gemm_nt_f32(
    const float* __restrict__ A, const float* __restrict__ W,
    const float* __restrict__ bias, float* __restrict__ out)
{
    __shared__ float As[64][65];
    __shared__ float Ws[64][65];
    const int tid = threadIdx.x;
    const int tx = tid & 15, ty = tid >> 4;
    const int n0 = blockIdx.x * 64;
    const int j0 = blockIdx.y * 64;
    float acc[4][4] = {};
    for (int k0 = 0; k0 < C_; k0 += 64) {
#pragma unroll
        for (int i = 0; i < 4; ++i) {
            int idx = tid + i * 256;
            int r = idx >> 4, c4 = (idx & 15) * 4;
            float4 fa = *(const float4*)(A + (size_t)(n0 + r) * C_ + k0 + c4);
            As[r][c4 + 0] = fa.x; As[r][c4 + 1] = fa.y;
            As[r][c4 + 2] = fa.z; As[r][c4 + 3] = fa.w;
            float4 fw = *(const float4*)(W + (size_t)(j0 + r) * C_ + k0 + c4);
            Ws[r][c4 + 0] = fw.x; Ws[r][c4 + 1] = fw.y;
            Ws[r][c4 + 2] = fw.z; Ws[r][c4 + 3] = fw.w;
        }
        __syncthreads();
#pragma unroll 8
        for (int kk = 0; kk < 64; ++kk) {
            float a[4], bf[4];
#pragma unroll
            for (int i = 0; i < 4; ++i) a[i] = As[ty * 4 + i][kk];
#pragma unroll
            for (int j = 0; j < 4; ++j) bf[j] = Ws[tx * 4 + j][kk];
#pragma unroll
            for (int i = 0; i < 4; ++i)
#pragma unroll
                for (int j = 0; j < 4; ++j)
                    acc[i][j] += a[i] * bf[j];
        }
        __syncthreads();
    }
    const int j = j0 + tx * 4;
    float4 b4 = *(const float4*)(bias + j);
#pragma unroll
    for (int i = 0; i < 4; ++i) {
        float4 o;
        o.x = acc[i][0] + b4.x; o.y = acc[i][1] + b4.y;
        o.z = acc[i][2] + b4.z; o.w = acc[i][3] + b4.w;
        *(float4*)(out + (size_t)(n0 + ty * 4 + i) * C_ + j) = o;
    }
}

// ---------------------------------------------------------------------------
// Flash-style memory attention.
// One block per (64 q-rows, head, batch). Online softmax over t-chunks of 64.
// k_comb[t] = t < L ? memory_kv[t,b,h,:64] : k[t-L,b,h,:]   (only t < L+pad valid)
// Valid-set depends on (t,b) only (user mask is consulted but is all-False).
// K and V share one LDS buffer (V loaded after S-compute) to fit 64 KB LDS.
// ---------------------------------------------------------------------------
__global__ __launch_bounds__(256) void mem_attn_f32(
    const float* __restrict__ qb, const float* __restrict__ kb,
    const float* __restrict__ vb, const float* __restrict__ mkv,
    const int* __restrict__ mlen, const int* __restrict__ padv,
    const unsigned char* __restrict__ maskb, float* __restrict__ xout)
{
    __shared__ float Qs[64][65];
    __shared__ float KVs[64][65];  // holds K chunk, then V chunk
    __shared__ float Ps[64][65];   // P transposed: Ps[t_local][row]
    const int tid = threadIdx.x;
    const int tx = tid & 15, ty = tid >> 4;
    const int s0 = blockIdx.x * 64;
    const int h  = blockIdx.y;
    const int b  = blockIdx.z;
    const int L  = mlen[b];
    const int P  = padv[b];
    const int tend = L + P;
    const float NEG = -1e30f;

    // Load Q tile: rows s0..s0+63, dims h*64..h*64+63
#pragma unroll
    for (int i = 0; i < 4; ++i) {
        int idx = tid + i * 256;
        int r = idx >> 4, c4 = (idx & 15) * 4;
        float4 f = *(const float4*)(qb + ((size_t)(s0 + r) * B_ + b) * C_ + h * HC_ + c4);
        Qs[r][c4 + 0] = f.x; Qs[r][c4 + 1] = f.y;
        Qs[r][c4 + 2] = f.z; Qs[r][c4 + 3] = f.w;
    }

    float Oacc[4][4] = {};
    float mrow[4] = {NEG, NEG, NEG, NEG};
    float lrow[4] = {0.f, 0.f, 0.f, 0.f};

    const int nch = (tend + 63) >> 6;
    for (int ci = 0; ci < nch; ++ci) {
        const int t0 = ci << 6;
        // ---- load K chunk (t0 .. t0+63) into KVs[t_local][hc] ----
#pragma unroll
        for (int i = 0; i < 4; ++i) {
            int idx = tid + i * 256;
            int tl = idx >> 4, c4 = (idx & 15) * 4;
            int t = t0 + tl;
            float4 f;
            if (t < L) {
                f = *(const float4*)(mkv + (((size_t)t * B_ + b) * H_ + h) * (2 * HC_) + c4);
            } else if (t - L < P) {
                f = *(const float4*)(kb + ((size_t)(t - L) * B_ + b) * C_ + h * HC_ + c4);
            } else {
                f = make_float4(0.f, 0.f, 0.f, 0.f);
            }
            KVs[tl][c4 + 0] = f.x; KVs[tl][c4 + 1] = f.y;
            KVs[tl][c4 + 2] = f.z; KVs[tl][c4 + 3] = f.w;
        }
        __syncthreads();  // K (and Q on first iter) visible

        // ---- S = (Q . K^T) * 0.125 with masking ----
        float sv[4][4] = {};
#pragma unroll 8
        for (int kk = 0; kk < 64; ++kk) {
            float a[4], kf[4];
#pragma unroll
            for (int i = 0; i < 4; ++i) a[i] = Qs[ty * 4 + i][kk];
#pragma unroll
            for (int j = 0; j < 4; ++j) kf[j] = KVs[tx * 4 + j][kk];
#pragma unroll
            for (int i = 0; i < 4; ++i)
#pragma unroll
                for (int j = 0; j < 4; ++j)
                    sv[i][j] += a[i] * kf[j];
        }

        // ---- online softmax update (per row; 16 tx-lanes share a row) ----
        float pvreg[4][4];
#pragma unroll
        for (int i = 0; i < 4; ++i) {
            const int s = s0 + ty * 4 + i;
            float rm = NEG;
#pragma unroll
            for (int j = 0; j < 4; ++j) {
                int t = t0 + tx * 4 + j;
                float val = sv[i][j] * 0.125f;
                bool masked;
                if (t < L) {
                    masked = false;
                } else {
                    int off = t - L;
                    masked = (off < P) ? (maskb[((size_t)s * KS_ + off) * B_ + b] != 0) : true;
                }
                val = masked ? NEG : val;
                sv[i][j] = val;
                rm = fmaxf(rm, val);
            }
            rm = fmaxf(rm, __shfl_xor(rm, 1, 16));
            rm = fmaxf(rm, __shfl_xor(rm, 2, 16));
            rm = fmaxf(rm, __shfl_xor(rm, 4, 16));
            rm = fmaxf(rm, __shfl_xor(rm, 8, 16));
            float nm = fmaxf(mrow[i], rm);
            float al = __expf(mrow[i] - nm);   // NEG-NEG -> exp(0)=1 (state empty, harmless)
            float rs = 0.f;
#pragma unroll
            for (int j = 0; j < 4; ++j) {
                float p = (sv[i][j] == NEG) ? 0.f : __expf(sv[i][j] - nm);
                pvreg[i][j] = p;
                rs += p;
            }
            rs += __shfl_xor(rs, 1, 16);
            rs += __shfl_xor(rs, 2, 16);
            rs += __shfl_xor(rs, 4, 16);
            rs += __shfl_xor(rs, 8, 16);
            lrow[i] = lrow[i] * al + rs;
            mrow[i] = nm;
#pragma unroll
            for (int j = 0; j < 4; ++j) Oacc[i][j] *= al;
        }
        __syncthreads();  // all threads done reading K from KVs

        // ---- load V chunk into KVs, write P^T to LDS ----
#pragma unroll
        for (int i = 0; i < 4; ++i) {
            int idx = tid + i * 256;
            int tl = idx >> 4, c4 = (idx & 15) * 4;
            int t = t0 + tl;
            float4 f;
            if (t < L) {
                f = *(const float4*)(mkv + (((size_t)t * B_ + b) * H_ + h) * (2 * HC_) + HC_ + c4);
            } else if (t - L < P) {
                f = *(const float4*)(vb + ((size_t)(t - L) * B_ + b) * C_ + h * HC_ + c4);
            } else {
                f = make_float4(0.f, 0.f, 0.f, 0.f);
            }
            KVs[tl][c4 + 0] = f.x; KVs[tl][c4 + 1] = f.y;
            KVs[tl][c4 + 2] = f.z; KVs[tl][c4 + 3] = f.w;
        }
#pragma unroll
        for (int i = 0; i < 4; ++i)
#pragma unroll
            for (int j = 0; j < 4; ++j)
                Ps[tx * 4 + j][ty * 4 + i] = pvreg[i][j];
        __syncthreads();  // V + P visible

        // ---- O += P . V ----
#pragma unroll 8
        for (int tl = 0; tl < 64; ++tl) {
            float p[4], v[4];
#pragma unroll
            for (int i = 0; i < 4; ++i) p[i] = Ps[tl][ty * 4 + i];
#pragma unroll
            for (int j = 0; j < 4; ++j) v[j] = KVs[tl][tx * 4 + j];
#pragma unroll
            for (int i = 0; i < 4; ++i)
#pragma unroll
                for (int j = 0; j < 4; ++j)
                    Oacc[i][j] += p[i] * v[j];
        }
        __syncthreads();  // done reading V/P before next chunk overwrites
    }

    // ---- epilogue: normalize (l==0 -> 0, matches nan_to_num) and store ----
#pragma unroll
    for (int i = 0; i < 4; ++i) {
        float inv = (lrow[i] > 0.f) ? 1.0f / lrow[i] : 0.f;
        float4 o;
        o.x = Oacc[i][0] * inv; o.y = Oacc[i][1] * inv;
        o.z = Oacc[i][2] * inv; o.w = Oacc[i][3] * inv;
        *(float4*)(xout + ((size_t)(s0 + ty * 4 + i) * B_ + b) * C_ + h * HC_ + tx * 4) = o;
    }
}

// ---------------------------------------------------------------------------
extern "C" void kernel_launch(void* const* d_in, const int* in_sizes, int n_in,
                              void* d_out, int out_size, void* d_ws, size_t ws_size,
                              hipStream_t stream)
{
    const float* xq   = (const float*)d_in[0];
    const int*   pad  = (const int*)d_in[1];
    const unsigned char* maskb = (const unsigned char*)d_in[2];  // all-False; byte-read safe under bool or int32 packing
    const int*   mlen = (const int*)d_in[3];
    const float* mkv  = (const float*)d_in[4];
    const float* Wq   = (const float*)d_in[5];
    const float* bq   = (const float*)d_in[6];
    const float* Wk   = (const float*)d_in[7];
    const float* bk   = (const float*)d_in[8];
    const float* Wv   = (const float*)d_in[9];
    const float* bv   = (const float*)d_in[10];
    const float* Wo   = (const float*)d_in[11];
    const float* bo   = (const float*)d_in[12];
    float* out = (float*)d_out;

    // Workspace: q, k, v, x buffers, each QS*B*C f32 = 16 MiB (64 MiB total)
    float* ws = (float*)d_ws;
    float* qbuf = ws;
    float* kbuf = qbuf + (size_t)QS_ * B_ * C_;
    float* vbuf = kbuf + (size_t)QS_ * B_ * C_;
    float* xbuf = vbuf + (size_t)QS_ * B_ * C_;

    dim3 gblk(256);
    dim3 ggemm(64, 16);   // 4096/64 x 1024/64
    gemm_nt_f32<<<ggemm, gblk, 0, stream>>>(xq, Wq, bq, qbuf);
    gemm_nt_f32<<<ggemm, gblk, 0, stream>>>(xq, Wk, bk, kbuf);
    gemm_nt_f32<<<ggemm, gblk, 0, stream>>>(xq, Wv, bv, vbuf);

    dim3 gattn(QS_ / 64, H_, B_);  // (8, 16, 8)
    mem_attn_f32<<<gattn, gblk, 0, stream>>>(qbuf, kbuf, vbuf, mkv, mlen, pad, maskb, xbuf);

    gemm_nt_f32<<<ggemm, gblk, 0, stream>>>(xbuf, Wo, bo, out);
}

// Round 2
// 740.359 us; speedup vs baseline: 1.6795x; 1.6795x over previous
//
#include <hip/hip_runtime.h>

// Problem constants (fixed by the reference's setup_inputs)
#define QS_ 512
#define B_  8
#define C_  1024
#define H_  16
#define HC_ 64
#define M_  1536
#define KS_ 512

typedef __attribute__((ext_vector_type(8))) short bf16x8;
typedef __attribute__((ext_vector_type(4))) float f32x4;

__device__ __forceinline__ short f2bf(float f) {
    unsigned u = __float_as_uint(f);
    unsigned r = (u + 0x7FFF + ((u >> 16) & 1)) >> 16;   // RNE
    return (short)r;
}

// ---------------------------------------------------------------------------
// bf16-MFMA NT GEMM: out[n][j] = sum_k A[n][k] * W[j][k] + bias[j]
// A: 4096x1024 f32 row-major, W: 1024x1024 f32 row-major (both converted to
// bf16 during LDS staging). 128x128 tile, BK=64, 4 waves, each wave owns a
// 64x64 quadrant as 4x4 grid of 16x16x32 MFMA tiles.
// LDS row stride 72 bf16 (144B = 36 dwords): <=2-way bank aliasing on both
// the b64 staging writes and b128 fragment reads (free per m136).
// ---------------------------------------------------------------------------
__global__ __launch_bounds__(256) void gemm_nt_bf16(
    const float* __restrict__ A, const float* __restrict__ W,
    const float* __restrict__ bias, float* __restrict__ out)
{
    __shared__ short As[128][72];
    __shared__ short Ws[128][72];
    const int tid  = threadIdx.x;
    const int lane = tid & 63;
    const int wave = tid >> 6;
    const int wm = (wave & 1) * 64;
    const int wn = (wave >> 1) * 64;
    const int lr = lane & 15;        // A row / B col within 16-tile
    const int quad = lane >> 4;      // k-offset selector (quad*8)
    const int n0 = blockIdx.x * 128;
    const int j0 = blockIdx.y * 128;

    f32x4 acc[4][4];
#pragma unroll
    for (int i = 0; i < 4; ++i)
#pragma unroll
        for (int j = 0; j < 4; ++j)
            acc[i][j] = (f32x4){0.f, 0.f, 0.f, 0.f};

    for (int k0 = 0; k0 < C_; k0 += 64) {
        // stage A and W tiles: 128 rows x 64 k, f32 -> bf16
#pragma unroll
        for (int p = 0; p < 8; ++p) {
            int flat = p * 256 + tid;           // 0..2047
            int r = flat >> 4;                  // 0..127
            int c4 = (flat & 15) * 4;           // 0..60
            float4 fa = *(const float4*)(A + (size_t)(n0 + r) * C_ + k0 + c4);
            union { short s[4]; long long ll; } ta;
            ta.s[0] = f2bf(fa.x); ta.s[1] = f2bf(fa.y);
            ta.s[2] = f2bf(fa.z); ta.s[3] = f2bf(fa.w);
            *(long long*)&As[r][c4] = ta.ll;
            float4 fw = *(const float4*)(W + (size_t)(j0 + r) * C_ + k0 + c4);
            union { short s[4]; long long ll; } tw;
            tw.s[0] = f2bf(fw.x); tw.s[1] = f2bf(fw.y);
            tw.s[2] = f2bf(fw.z); tw.s[3] = f2bf(fw.w);
            *(long long*)&Ws[r][c4] = tw.ll;
        }
        __syncthreads();
#pragma unroll
        for (int ks = 0; ks < 2; ++ks) {        // two k-steps of 32
            const int kk = ks * 32 + quad * 8;
            bf16x8 afrag[4], bfrag[4];
#pragma unroll
            for (int im = 0; im < 4; ++im)
                afrag[im] = *(const bf16x8*)&As[wm + im * 16 + lr][kk];
#pragma unroll
            for (int jn = 0; jn < 4; ++jn)
                bfrag[jn] = *(const bf16x8*)&Ws[wn + jn * 16 + lr][kk];
#pragma unroll
            for (int im = 0; im < 4; ++im)
#pragma unroll
                for (int jn = 0; jn < 4; ++jn)
                    acc[im][jn] = __builtin_amdgcn_mfma_f32_16x16x32_bf16(
                        afrag[im], bfrag[jn], acc[im][jn], 0, 0, 0);
        }
        __syncthreads();
    }

    // epilogue: D layout col=lane&15, row=quad*4+reg
#pragma unroll
    for (int jn = 0; jn < 4; ++jn) {
        const int col = j0 + wn + jn * 16 + lr;
        const float bv = bias[col];
#pragma unroll
        for (int im = 0; im < 4; ++im) {
            const int row = n0 + wm + im * 16 + quad * 4;
#pragma unroll
            for (int r = 0; r < 4; ++r)
                out[(size_t)(row + r) * C_ + col] = acc[im][jn][r] + bv;
        }
    }
}

// ---------------------------------------------------------------------------
// Flash-style memory attention (unchanged from round 1, f32).
// ---------------------------------------------------------------------------
__global__ __launch_bounds__(256) void mem_attn_f32(
    const float* __restrict__ qb, const float* __restrict__ kb,
    const float* __restrict__ vb, const float* __restrict__ mkv,
    const int* __restrict__ mlen, const int* __restrict__ padv,
    const unsigned char* __restrict__ maskb, float* __restrict__ xout)
{
    __shared__ float Qs[64][65];
    __shared__ float KVs[64][65];  // holds K chunk, then V chunk
    __shared__ float Ps[64][65];   // P transposed: Ps[t_local][row]
    const int tid = threadIdx.x;
    const int tx = tid & 15, ty = tid >> 4;
    const int s0 = blockIdx.x * 64;
    const int h  = blockIdx.y;
    const int b  = blockIdx.z;
    const int L  = mlen[b];
    const int P  = padv[b];
    const int tend = L + P;
    const float NEG = -1e30f;

#pragma unroll
    for (int i = 0; i < 4; ++i) {
        int idx = tid + i * 256;
        int r = idx >> 4, c4 = (idx & 15) * 4;
        float4 f = *(const float4*)(qb + ((size_t)(s0 + r) * B_ + b) * C_ + h * HC_ + c4);
        Qs[r][c4 + 0] = f.x; Qs[r][c4 + 1] = f.y;
        Qs[r][c4 + 2] = f.z; Qs[r][c4 + 3] = f.w;
    }

    float Oacc[4][4] = {};
    float mrow[4] = {NEG, NEG, NEG, NEG};
    float lrow[4] = {0.f, 0.f, 0.f, 0.f};

    const int nch = (tend + 63) >> 6;
    for (int ci = 0; ci < nch; ++ci) {
        const int t0 = ci << 6;
#pragma unroll
        for (int i = 0; i < 4; ++i) {
            int idx = tid + i * 256;
            int tl = idx >> 4, c4 = (idx & 15) * 4;
            int t = t0 + tl;
            float4 f;
            if (t < L) {
                f = *(const float4*)(mkv + (((size_t)t * B_ + b) * H_ + h) * (2 * HC_) + c4);
            } else if (t - L < P) {
                f = *(const float4*)(kb + ((size_t)(t - L) * B_ + b) * C_ + h * HC_ + c4);
            } else {
                f = make_float4(0.f, 0.f, 0.f, 0.f);
            }
            KVs[tl][c4 + 0] = f.x; KVs[tl][c4 + 1] = f.y;
            KVs[tl][c4 + 2] = f.z; KVs[tl][c4 + 3] = f.w;
        }
        __syncthreads();

        float sv[4][4] = {};
#pragma unroll 8
        for (int kk = 0; kk < 64; ++kk) {
            float a[4], kf[4];
#pragma unroll
            for (int i = 0; i < 4; ++i) a[i] = Qs[ty * 4 + i][kk];
#pragma unroll
            for (int j = 0; j < 4; ++j) kf[j] = KVs[tx * 4 + j][kk];
#pragma unroll
            for (int i = 0; i < 4; ++i)
#pragma unroll
                for (int j = 0; j < 4; ++j)
                    sv[i][j] += a[i] * kf[j];
        }

        float pvreg[4][4];
#pragma unroll
        for (int i = 0; i < 4; ++i) {
            const int s = s0 + ty * 4 + i;
            float rm = NEG;
#pragma unroll
            for (int j = 0; j < 4; ++j) {
                int t = t0 + tx * 4 + j;
                float val = sv[i][j] * 0.125f;
                bool masked;
                if (t < L) {
                    masked = false;
                } else {
                    int off = t - L;
                    masked = (off < P) ? (maskb[((size_t)s * KS_ + off) * B_ + b] != 0) : true;
                }
                val = masked ? NEG : val;
                sv[i][j] = val;
                rm = fmaxf(rm, val);
            }
            rm = fmaxf(rm, __shfl_xor(rm, 1, 16));
            rm = fmaxf(rm, __shfl_xor(rm, 2, 16));
            rm = fmaxf(rm, __shfl_xor(rm, 4, 16));
            rm = fmaxf(rm, __shfl_xor(rm, 8, 16));
            float nm = fmaxf(mrow[i], rm);
            float al = __expf(mrow[i] - nm);
            float rs = 0.f;
#pragma unroll
            for (int j = 0; j < 4; ++j) {
                float p = (sv[i][j] == NEG) ? 0.f : __expf(sv[i][j] - nm);
                pvreg[i][j] = p;
                rs += p;
            }
            rs += __shfl_xor(rs, 1, 16);
            rs += __shfl_xor(rs, 2, 16);
            rs += __shfl_xor(rs, 4, 16);
            rs += __shfl_xor(rs, 8, 16);
            lrow[i] = lrow[i] * al + rs;
            mrow[i] = nm;
#pragma unroll
            for (int j = 0; j < 4; ++j) Oacc[i][j] *= al;
        }
        __syncthreads();

#pragma unroll
        for (int i = 0; i < 4; ++i) {
            int idx = tid + i * 256;
            int tl = idx >> 4, c4 = (idx & 15) * 4;
            int t = t0 + tl;
            float4 f;
            if (t < L) {
                f = *(const float4*)(mkv + (((size_t)t * B_ + b) * H_ + h) * (2 * HC_) + HC_ + c4);
            } else if (t - L < P) {
                f = *(const float4*)(vb + ((size_t)(t - L) * B_ + b) * C_ + h * HC_ + c4);
            } else {
                f = make_float4(0.f, 0.f, 0.f, 0.f);
            }
            KVs[tl][c4 + 0] = f.x; KVs[tl][c4 + 1] = f.y;
            KVs[tl][c4 + 2] = f.z; KVs[tl][c4 + 3] = f.w;
        }
#pragma unroll
        for (int i = 0; i < 4; ++i)
#pragma unroll
            for (int j = 0; j < 4; ++j)
                Ps[tx * 4 + j][ty * 4 + i] = pvreg[i][j];
        __syncthreads();

#pragma unroll 8
        for (int tl = 0; tl < 64; ++tl) {
            float p[4], v[4];
#pragma unroll
            for (int i = 0; i < 4; ++i) p[i] = Ps[tl][ty * 4 + i];
#pragma unroll
            for (int j = 0; j < 4; ++j) v[j] = KVs[tl][tx * 4 + j];
#pragma unroll
            for (int i = 0; i < 4; ++i)
#pragma unroll
                for (int j = 0; j < 4; ++j)
                    Oacc[i][j] += p[i] * v[j];
        }
        __syncthreads();
    }

#pragma unroll
    for (int i = 0; i < 4; ++i) {
        float inv = (lrow[i] > 0.f) ? 1.0f / lrow[i] : 0.f;
        float4 o;
        o.x = Oacc[i][0] * inv; o.y = Oacc[i][1] * inv;
        o.z = Oacc[i][2] * inv; o.w = Oacc[i][3] * inv;
        *(float4*)(xout + ((size_t)(s0 + ty * 4 + i) * B_ + b) * C_ + h * HC_ + tx * 4) = o;
    }
}

// ---------------------------------------------------------------------------
extern "C" void kernel_launch(void* const* d_in, const int* in_sizes, int n_in,
                              void* d_out, int out_size, void* d_ws, size_t ws_size,
                              hipStream_t stream)
{
    const float* xq   = (const float*)d_in[0];
    const int*   pad  = (const int*)d_in[1];
    const unsigned char* maskb = (const unsigned char*)d_in[2];
    const int*   mlen = (const int*)d_in[3];
    const float* mkv  = (const float*)d_in[4];
    const float* Wq   = (const float*)d_in[5];
    const float* bq   = (const float*)d_in[6];
    const float* Wk   = (const float*)d_in[7];
    const float* bk   = (const float*)d_in[8];
    const float* Wv   = (const float*)d_in[9];
    const float* bv   = (const float*)d_in[10];
    const float* Wo   = (const float*)d_in[11];
    const float* bo   = (const float*)d_in[12];
    float* out = (float*)d_out;

    float* ws = (float*)d_ws;
    float* qbuf = ws;
    float* kbuf = qbuf + (size_t)QS_ * B_ * C_;
    float* vbuf = kbuf + (size_t)QS_ * B_ * C_;
    float* xbuf = vbuf + (size_t)QS_ * B_ * C_;

    dim3 gblk(256);
    dim3 ggemm(32, 8);   // 4096/128 x 1024/128
    gemm_nt_bf16<<<ggemm, gblk, 0, stream>>>(xq, Wq, bq, qbuf);
    gemm_nt_bf16<<<ggemm, gblk, 0, stream>>>(xq, Wk, bk, kbuf);
    gemm_nt_bf16<<<ggemm, gblk, 0, stream>>>(xq, Wv, bv, vbuf);

    dim3 gattn(QS_ / 64, H_, B_);  // (8, 16, 8)
    mem_attn_f32<<<gattn, gblk, 0, stream>>>(qbuf, kbuf, vbuf, mkv, mlen, pad, maskb, xbuf);

    gemm_nt_bf16<<<ggemm, gblk, 0, stream>>>(xbuf, Wo, bo, out);
}

// Round 3
// 565.638 us; speedup vs baseline: 2.1983x; 1.3089x over previous
//
#include <hip/hip_runtime.h>

// Problem constants (fixed by the reference's setup_inputs)
#define QS_ 512
#define B_  8
#define C_  1024
#define H_  16
#define HC_ 64
#define M_  1536
#define KS_ 512

typedef __attribute__((ext_vector_type(8))) short bf16x8;
typedef __attribute__((ext_vector_type(4))) float f32x4;

__device__ __forceinline__ short f2bf(float f) {
    unsigned u = __float_as_uint(f);
    unsigned r = (u + 0x7FFF + ((u >> 16) & 1)) >> 16;   // RNE
    return (short)r;
}

// ---------------------------------------------------------------------------
// bf16-MFMA NT GEMM: out[n][j] = sum_k A[n][k] * W[j][k] + bias[j]
// A: 4096x1024 f32, W: 1024x1024 f32 (converted to bf16 at LDS staging).
// 128x128 tile, BK=64, 4 waves, 4x4 16x16x32 MFMA tiles per wave.
// BF16OUT: store output as bf16 (for q/k/v feeding the MFMA attention).
// ---------------------------------------------------------------------------
template <bool BF16OUT>
__global__ __launch_bounds__(256) void gemm_nt_bf16(
    const float* __restrict__ A, const float* __restrict__ W,
    const float* __restrict__ bias, void* __restrict__ outv)
{
    __shared__ short As[128][72];
    __shared__ short Ws[128][72];
    const int tid  = threadIdx.x;
    const int lane = tid & 63;
    const int wave = tid >> 6;
    const int wm = (wave & 1) * 64;
    const int wn = (wave >> 1) * 64;
    const int lr = lane & 15;
    const int quad = lane >> 4;
    const int n0 = blockIdx.x * 128;
    const int j0 = blockIdx.y * 128;

    f32x4 acc[4][4];
#pragma unroll
    for (int i = 0; i < 4; ++i)
#pragma unroll
        for (int j = 0; j < 4; ++j)
            acc[i][j] = (f32x4){0.f, 0.f, 0.f, 0.f};

    for (int k0 = 0; k0 < C_; k0 += 64) {
#pragma unroll
        for (int p = 0; p < 8; ++p) {
            int flat = p * 256 + tid;
            int r = flat >> 4;
            int c4 = (flat & 15) * 4;
            float4 fa = *(const float4*)(A + (size_t)(n0 + r) * C_ + k0 + c4);
            union { short s[4]; long long ll; } ta;
            ta.s[0] = f2bf(fa.x); ta.s[1] = f2bf(fa.y);
            ta.s[2] = f2bf(fa.z); ta.s[3] = f2bf(fa.w);
            *(long long*)&As[r][c4] = ta.ll;
            float4 fw = *(const float4*)(W + (size_t)(j0 + r) * C_ + k0 + c4);
            union { short s[4]; long long ll; } tw;
            tw.s[0] = f2bf(fw.x); tw.s[1] = f2bf(fw.y);
            tw.s[2] = f2bf(fw.z); tw.s[3] = f2bf(fw.w);
            *(long long*)&Ws[r][c4] = tw.ll;
        }
        __syncthreads();
#pragma unroll
        for (int ks = 0; ks < 2; ++ks) {
            const int kk = ks * 32 + quad * 8;
            bf16x8 afrag[4], bfrag[4];
#pragma unroll
            for (int im = 0; im < 4; ++im)
                afrag[im] = *(const bf16x8*)&As[wm + im * 16 + lr][kk];
#pragma unroll
            for (int jn = 0; jn < 4; ++jn)
                bfrag[jn] = *(const bf16x8*)&Ws[wn + jn * 16 + lr][kk];
#pragma unroll
            for (int im = 0; im < 4; ++im)
#pragma unroll
                for (int jn = 0; jn < 4; ++jn)
                    acc[im][jn] = __builtin_amdgcn_mfma_f32_16x16x32_bf16(
                        afrag[im], bfrag[jn], acc[im][jn], 0, 0, 0);
        }
        __syncthreads();
    }

#pragma unroll
    for (int jn = 0; jn < 4; ++jn) {
        const int col = j0 + wn + jn * 16 + lr;
        const float bv = bias[col];
#pragma unroll
        for (int im = 0; im < 4; ++im) {
            const int row = n0 + wm + im * 16 + quad * 4;
#pragma unroll
            for (int r = 0; r < 4; ++r) {
                float v = acc[im][jn][r] + bv;
                if (BF16OUT)
                    ((short*)outv)[(size_t)(row + r) * C_ + col] = f2bf(v);
                else
                    ((float*)outv)[(size_t)(row + r) * C_ + col] = v;
            }
        }
    }
}

// ---------------------------------------------------------------------------
// MFMA flash attention. Block = 64 q-rows x (h,b); 4 waves, wave owns 16 q.
// Per 64-t chunk: stage K [t][hc] and V transposed [hc][t] (bf16), QK^T via
// 16x16x32 MFMA, online softmax in C-layout registers, P -> LDS (A-layout),
// PV via MFMA. k_comb[t] = t<L ? memory_kv : projected k at t-L (t<L+P).
// ---------------------------------------------------------------------------
__global__ __launch_bounds__(256) void mem_attn_mfma(
    const short* __restrict__ qb, const short* __restrict__ kb,
    const short* __restrict__ vb, const float* __restrict__ mkv,
    const int* __restrict__ mlen, const int* __restrict__ padv,
    const unsigned char* __restrict__ maskb, float* __restrict__ xout)
{
    __shared__ short Qs[64][64];   // [q_local][hc]   (m97-trusted unpadded)
    __shared__ short Ks[64][64];   // [t_local][hc]
    __shared__ short Vt[64][72];   // [hc][t_local]   stride 72 -> 16B-aligned rows
    __shared__ short Pl[64][72];   // [q_local][t_local]
    const int tid  = threadIdx.x;
    const int lane = tid & 63;
    const int wave = tid >> 6;
    const int lr   = lane & 15;
    const int quad = lane >> 4;
    const int s0 = blockIdx.x * 64;
    const int h  = blockIdx.y;
    const int b  = blockIdx.z;
    const int L  = mlen[b];
    const int P  = padv[b];
    const int tend = L + P;
    const float NEG = -1e30f;

    // ---- load Q tile (bf16): 64 rows x 128 B ----
#pragma unroll
    for (int i = 0; i < 2; ++i) {
        int seg = i * 256 + tid;            // 0..511
        int r = seg >> 3, off = (seg & 7) * 8;
        const short* src = qb + ((size_t)(s0 + r) * B_ + b) * C_ + h * HC_ + off;
        *(uint4*)&Qs[r][off] = *(const uint4*)src;
    }

    f32x4 Oacc[4];
#pragma unroll
    for (int i = 0; i < 4; ++i) Oacc[i] = (f32x4){0.f, 0.f, 0.f, 0.f};
    float mrow[4] = {NEG, NEG, NEG, NEG};
    float lrow[4] = {0.f, 0.f, 0.f, 0.f};

    const int tl = tid >> 2;      // staging row 0..63
    const int cg = tid & 3;       // col group
    const int c0 = cg * 16;

    const int nch = (tend + 63) >> 6;
    for (int ci = 0; ci < nch; ++ci) {
        const int t0 = ci << 6;
        const int t  = t0 + tl;
        // ---- stage K row tl, cols c0..c0+15 ----
        {
            short tk[16];
            if (t < L) {
                const float4* src = (const float4*)(mkv + (((size_t)t * B_ + b) * H_ + h) * (2 * HC_) + c0);
#pragma unroll
                for (int j = 0; j < 4; ++j) {
                    float4 f = src[j];
                    tk[j * 4 + 0] = f2bf(f.x); tk[j * 4 + 1] = f2bf(f.y);
                    tk[j * 4 + 2] = f2bf(f.z); tk[j * 4 + 3] = f2bf(f.w);
                }
            } else if (t - L < P) {
                const uint4* src = (const uint4*)(kb + ((size_t)(t - L) * B_ + b) * C_ + h * HC_ + c0);
                *(uint4*)&tk[0] = src[0];
                *(uint4*)&tk[8] = src[1];
            } else {
#pragma unroll
                for (int j = 0; j < 16; ++j) tk[j] = 0;
            }
            *(uint4*)&Ks[tl][c0]     = *(uint4*)&tk[0];
            *(uint4*)&Ks[tl][c0 + 8] = *(uint4*)&tk[8];
        }
        // ---- stage V transposed: Vt[c0+j][tl] ----
        {
            short tv[16];
            if (t < L) {
                const float4* src = (const float4*)(mkv + (((size_t)t * B_ + b) * H_ + h) * (2 * HC_) + HC_ + c0);
#pragma unroll
                for (int j = 0; j < 4; ++j) {
                    float4 f = src[j];
                    tv[j * 4 + 0] = f2bf(f.x); tv[j * 4 + 1] = f2bf(f.y);
                    tv[j * 4 + 2] = f2bf(f.z); tv[j * 4 + 3] = f2bf(f.w);
                }
            } else if (t - L < P) {
                const uint4* src = (const uint4*)(vb + ((size_t)(t - L) * B_ + b) * C_ + h * HC_ + c0);
                *(uint4*)&tv[0] = src[0];
                *(uint4*)&tv[8] = src[1];
            } else {
#pragma unroll
                for (int j = 0; j < 16; ++j) tv[j] = 0;
            }
            // rotate write order by cg to de-collide banks
#pragma unroll
            for (int jj = 0; jj < 16; ++jj) {
                int j = (jj + cg) & 15;
                Vt[c0 + j][tl] = tv[j];
            }
        }
        __syncthreads();

        // ---- S = Q . K^T (4 t-tiles of 16x16, K-dim 64) ----
        bf16x8 aq0 = *(const bf16x8*)&Qs[wave * 16 + lr][quad * 8];
        bf16x8 aq1 = *(const bf16x8*)&Qs[wave * 16 + lr][32 + quad * 8];
        f32x4 S[4];
#pragma unroll
        for (int tt = 0; tt < 4; ++tt) {
            bf16x8 bk0 = *(const bf16x8*)&Ks[tt * 16 + lr][quad * 8];
            bf16x8 bk1 = *(const bf16x8*)&Ks[tt * 16 + lr][32 + quad * 8];
            f32x4 z = (f32x4){0.f, 0.f, 0.f, 0.f};
            z = __builtin_amdgcn_mfma_f32_16x16x32_bf16(aq0, bk0, z, 0, 0, 0);
            S[tt] = __builtin_amdgcn_mfma_f32_16x16x32_bf16(aq1, bk1, z, 0, 0, 0);
        }

        // ---- mask + online softmax (C layout: row=quad*4+r, col=lane&15) ----
        float Sv[4][4];           // [tt][r]
        float rowmax[4] = {NEG, NEG, NEG, NEG};
#pragma unroll
        for (int tt = 0; tt < 4; ++tt) {
            const int tcol = t0 + tt * 16 + lr;
            const bool in_mem = tcol < L;
            const int off = tcol - L;
            const bool in_new = !in_mem && (off < P);
#pragma unroll
            for (int r = 0; r < 4; ++r) {
                float val = S[tt][r] * 0.125f;
                bool masked;
                if (in_mem) masked = false;
                else if (in_new) {
                    const int s = s0 + wave * 16 + quad * 4 + r;
                    masked = maskb[((size_t)s * KS_ + off) * B_ + b] != 0;
                } else masked = true;
                val = masked ? NEG : val;
                Sv[tt][r] = val;
                rowmax[r] = fmaxf(rowmax[r], val);
            }
        }
#pragma unroll
        for (int r = 0; r < 4; ++r) {
            float rm = rowmax[r];
            rm = fmaxf(rm, __shfl_xor(rm, 1, 16));
            rm = fmaxf(rm, __shfl_xor(rm, 2, 16));
            rm = fmaxf(rm, __shfl_xor(rm, 4, 16));
            rm = fmaxf(rm, __shfl_xor(rm, 8, 16));
            rowmax[r] = rm;
        }
        float pv[4][4];           // [tt][r]
#pragma unroll
        for (int r = 0; r < 4; ++r) {
            float nm = fmaxf(mrow[r], rowmax[r]);
            float al = __expf(mrow[r] - nm);
            float rs = 0.f;
#pragma unroll
            for (int tt = 0; tt < 4; ++tt) {
                float p = (Sv[tt][r] == NEG) ? 0.f : __expf(Sv[tt][r] - nm);
                pv[tt][r] = p;
                rs += p;
            }
            rs += __shfl_xor(rs, 1, 16);
            rs += __shfl_xor(rs, 2, 16);
            rs += __shfl_xor(rs, 4, 16);
            rs += __shfl_xor(rs, 8, 16);
            lrow[r] = lrow[r] * al + rs;
            mrow[r] = nm;
#pragma unroll
            for (int ht = 0; ht < 4; ++ht) Oacc[ht][r] *= al;
        }
        // ---- write P (bf16) to LDS A-layout; quad-rotated tile order ----
#pragma unroll
        for (int jj = 0; jj < 4; ++jj) {
            int tt = (jj + quad) & 3;
#pragma unroll
            for (int r = 0; r < 4; ++r)
                Pl[wave * 16 + quad * 4 + r][tt * 16 + lr] = f2bf(pv[tt][r]);
        }
        __syncthreads();

        // ---- O += P . V ----
        bf16x8 ap0 = *(const bf16x8*)&Pl[wave * 16 + lr][quad * 8];
        bf16x8 ap1 = *(const bf16x8*)&Pl[wave * 16 + lr][32 + quad * 8];
#pragma unroll
        for (int ht = 0; ht < 4; ++ht) {
            bf16x8 bv0 = *(const bf16x8*)&Vt[ht * 16 + lr][quad * 8];
            bf16x8 bv1 = *(const bf16x8*)&Vt[ht * 16 + lr][32 + quad * 8];
            Oacc[ht] = __builtin_amdgcn_mfma_f32_16x16x32_bf16(ap0, bv0, Oacc[ht], 0, 0, 0);
            Oacc[ht] = __builtin_amdgcn_mfma_f32_16x16x32_bf16(ap1, bv1, Oacc[ht], 0, 0, 0);
        }
        __syncthreads();   // PV reads done before next chunk overwrites Ks/Vt
    }

    // ---- epilogue ----
#pragma unroll
    for (int r = 0; r < 4; ++r) {
        float inv = (lrow[r] > 0.f) ? 1.0f / lrow[r] : 0.f;
        const int s = s0 + wave * 16 + quad * 4 + r;
#pragma unroll
        for (int ht = 0; ht < 4; ++ht)
            xout[((size_t)s * B_ + b) * C_ + h * HC_ + ht * 16 + lr] = Oacc[ht][r] * inv;
    }
}

// ---------------------------------------------------------------------------
extern "C" void kernel_launch(void* const* d_in, const int* in_sizes, int n_in,
                              void* d_out, int out_size, void* d_ws, size_t ws_size,
                              hipStream_t stream)
{
    const float* xq   = (const float*)d_in[0];
    const int*   pad  = (const int*)d_in[1];
    const unsigned char* maskb = (const unsigned char*)d_in[2];
    const int*   mlen = (const int*)d_in[3];
    const float* mkv  = (const float*)d_in[4];
    const float* Wq   = (const float*)d_in[5];
    const float* bq   = (const float*)d_in[6];
    const float* Wk   = (const float*)d_in[7];
    const float* bk   = (const float*)d_in[8];
    const float* Wv   = (const float*)d_in[9];
    const float* bv   = (const float*)d_in[10];
    const float* Wo   = (const float*)d_in[11];
    const float* bo   = (const float*)d_in[12];
    float* out = (float*)d_out;

    // ws: qbuf/kbuf/vbuf bf16 (8 MB each), xbuf f32 (16 MB)
    short* qbuf = (short*)d_ws;
    short* kbuf = qbuf + (size_t)QS_ * B_ * C_;
    short* vbuf = kbuf + (size_t)QS_ * B_ * C_;
    float* xbuf = (float*)(vbuf + (size_t)QS_ * B_ * C_);

    dim3 gblk(256);
    dim3 ggemm(32, 8);   // 4096/128 x 1024/128
    gemm_nt_bf16<true><<<ggemm, gblk, 0, stream>>>(xq, Wq, bq, qbuf);
    gemm_nt_bf16<true><<<ggemm, gblk, 0, stream>>>(xq, Wk, bk, kbuf);
    gemm_nt_bf16<true><<<ggemm, gblk, 0, stream>>>(xq, Wv, bv, vbuf);

    dim3 gattn(QS_ / 64, H_, B_);  // (8, 16, 8)
    mem_attn_mfma<<<gattn, gblk, 0, stream>>>(qbuf, kbuf, vbuf, mkv, mlen, pad, maskb, xbuf);

    gemm_nt_bf16<false><<<ggemm, gblk, 0, stream>>>(xbuf, Wo, bo, out);
}